// Round 1
// baseline (128.429 us; speedup 1.0000x reference)
//
#include <hip/hip_runtime.h>

// ---------------------------------------------------------------------------
// ConvQuantizationWrapper: exact integer reformulation, MFMA i8, fully fused.
// out = [conv3x3(q_in, tc(q_w)) + zp*conv3x3(ones, q_w)] / (sa*sw) + bias
//   q_in = clip(round(x*sa - zp), 0, 255) (u8);  q_w = round(w*sw)
//
// R5 (this round): quant_a fused INTO conv. Previous pipeline was two serial
// memory passes (quant 51.4MB->13.8MB, conv 19.7MB->51.4MB), each ~41us and
// ~4x above its roofline; the qa intermediate forced an HBM round-trip and
// full pass serialization. Now each conv block quantizes its own 6 input rows
// (x fp32 NCHW -> i8 "NHWC" in LDS) using quant_a's proven two-stage byte
// transpose (stride-68 scatter buffer -> vector repack), 2 rows/pass x 3
// passes, then runs the unchanged MFMA phase. Border handling moves from
// explicit pad rows in global qa to predicated zero rows in LDS.
// ---------------------------------------------------------------------------

typedef int v4i __attribute__((ext_vector_type(4)));

// ---- fused weight prep: quantize + 9-case border-correction table ----
// corr_tab[case][o], case = vcase*3 + hcase; vcase: 0 interior, 1 top(h==0),
// 2 bottom(h==55); hcase: 0 interior, 1 left(w==0), 2 right(w==55).
// corr = sum over in-range taps of (128*sum_c tc(q_w) + zp*sum_c q_w).
__global__ __launch_bounds__(64) void prep_wq(const float* __restrict__ wt,
                                              const float* __restrict__ sw_p,
                                              const float* __restrict__ zp_p,
                                              signed char* __restrict__ w8,
                                              float* __restrict__ corr_tab) {
  const int o = blockIdx.x;             // 0..63
  const int i = threadIdx.x;            // input channel 0..63
  const float sw = sw_p[0];
  const float* wp = wt + (size_t)(o * 64 + i) * 9;
  int q[9];
#pragma unroll
  for (int k = 0; k < 9; ++k) q[k] = (int)rintf(wp[k] * sw);
#pragma unroll
  for (int k = 0; k < 9; ++k)
    w8[(o * 9 + k) * 64 + i] = (signed char)(q[k] & 255);

  int stc[9], srw[9];
#pragma unroll
  for (int k = 0; k < 9; ++k) {
    int a = (int)(signed char)(q[k] & 255);   // two's-complement i8 value
    int b = q[k];
#pragma unroll
    for (int off = 32; off; off >>= 1) {      // xor butterfly: sum in ALL lanes
      a += __shfl_xor(a, off);
      b += __shfl_xor(b, off);
    }
    stc[k] = a; srw[k] = b;
  }
  const float zp = zp_p[0];
  if (i < 9) {                          // lane i computes border case i
    const int v = i / 3, hc = i % 3;
    float corr = 0.0f;
#pragma unroll
    for (int k = 0; k < 9; ++k) {
      const int kh = k / 3, kw = k % 3;
      const bool drop = (v == 1 && kh == 0) || (v == 2 && kh == 2) ||
                        (hc == 1 && kw == 0) || (hc == 2 && kw == 2);
      if (!drop) corr += 128.0f * (float)stc[k] + zp * (float)srw[k];
    }
    corr_tab[i * 64 + o] = corr;
  }
}

// ---- fused quantize + conv: LDS-staged implicit GEMM on mfma_i32_16x16x64 ----
// grid (14, 64): block = one n, 4 output rows (224 px), all 64 och.
// Phase 1 (x3 passes of 2 rows): load x fp32 (float4, coalesced), quantize to
// (q_in-128) i8, byte-scatter into stride-68 transpose buffer, repack as
// uint4 into qa LDS [6 rows][58 cols][64 ch] (rows outside image -> zeros,
// cols 0/57 -> zeros). Pass 0 also stages the corr table.
// Phase 2: 4 waves = (px-half 0/1) x (och-pair 0/1). Wave: 7 M-tiles of
// 16 px; per tile 9 ds_read_b128 A-frags, each feeding 2 MFMAs (och oa, oa+16).
__global__ __launch_bounds__(256, 4) void conv_fused(
    const float* __restrict__ x, const signed char* __restrict__ w8,
    const float* __restrict__ corr_tab, const float* __restrict__ bias,
    const float* __restrict__ sa_p, const float* __restrict__ sw_p,
    const float* __restrict__ zp_p, float* __restrict__ out) {
  __shared__ __align__(16) signed char lds[32192];
  // [0, 22272)      : qa  [6][58][64] i8   (padded row h0+r, col w+1, ch)
  // [22272, 24576)  : corr table, 9*64 fp32
  // [24576, 32192)  : transpose buffer [2][56 px][stride 68] bytes
  signed char* const trbuf = lds + 24576;

  const int tid = threadIdx.x;
  const int n = blockIdx.y;
  const int h0 = blockIdx.x * 4;        // output rows h0..h0+3; qa rows h0..h0+5
  const float sa = sa_p[0], zp = zp_p[0];
  const float* xim = x + (size_t)n * 200704;    // 64 * 3136

  // ---- phase 1: quantize 6 padded rows into LDS (2 rows per pass) ----
#pragma unroll 1
  for (int p = 0; p < 3; ++p) {
    const int ihb = h0 - 1 + 2 * p;     // input row of qa row 2p
#pragma unroll
    for (int it = 0; it < 7; ++it) {
      const int idx = tid + 256 * it;   // 0..1791: [r][c][w4]
      const int r = idx >= 896;
      const int rem = idx - 896 * r;
      const int c = (rem * 2341) >> 15; // rem / 14  (exact for rem < 896)
      const int w4 = rem - c * 14;
      const int ih = ihb + r;
      const bool valid = (unsigned)ih < 56u;
      float4 v = make_float4(0.0f, 0.0f, 0.0f, 0.0f);
      if (valid)
        v = *(const float4*)(xim + (size_t)c * 3136 + ih * 56 + w4 * 4);
      signed char* dst = trbuf + r * 3808 + w4 * 272 + c;  // [(4*w4+e)*68 + c]
      const float vv[4] = {v.x, v.y, v.z, v.w};
#pragma unroll
      for (int e = 0; e < 4; ++e) {
        signed char b = 0;
        if (valid) {
          float tq;
          {
#pragma clang fp contract(off)
            tq = vv[e] * sa - zp;       // match ref: mul then sub, no fma
          }
          float qf = rintf(tq);         // half-to-even, like jnp.round
          qf = fminf(fmaxf(qf, 0.0f), 255.0f);
          b = (signed char)((int)qf - 128);
        }
        dst[e * 68] = b;
      }
    }
    __syncthreads();
    const int cnt = p ? 464 : 608;      // pass 0 also copies corr (144 uint4)
#pragma unroll
    for (int it = 0; it < 3; ++it) {
      const int idx = tid + 256 * it;
      if (idx < 448) {                  // interior: 2 rows x 56 px x 16B quads
        const int r = idx >= 224;
        const int u = idx - 224 * r;
        const int w = u >> 2, q2 = u & 3;
        const unsigned* s = (const unsigned*)(trbuf + r * 3808 + w * 68 + q2 * 16);
        const uint4 vv = make_uint4(s[0], s[1], s[2], s[3]);
        *((uint4*)(lds + ((2 * p + r) * 58 + w + 1) * 64 + q2 * 16)) = vv;
      } else if (idx < 464) {           // col pads: col 0 and col 57, both rows
        const int p2 = idx - 448;
        const int r = p2 >> 3;
        const int side = (p2 >> 2) & 1;
        const int j = p2 & 3;
        *((uint4*)(lds + ((2 * p + r) * 58 + side * 57) * 64 + j * 16)) =
            make_uint4(0, 0, 0, 0);
      } else if (idx < cnt) {           // corr table (pass 0 only)
        ((uint4*)(lds + 22272))[idx - 464] = ((const uint4*)corr_tab)[idx - 464];
      }
    }
    __syncthreads();
  }

  // ---- phase 2: MFMA implicit GEMM (unchanged from previous round) ----
  const int lane = tid & 63;
  const int wv = tid >> 6;
  const int phalf = wv & 1;             // px offset 112*phalf
  const int ogp = wv >> 1;              // och 32*ogp
  const int ln = lane & 15;
  const int kg = lane >> 4;             // k-group: bytes kg*16..kg*16+15
  const int oa = ogp * 32 + ln;         // first och; second is oa+16

  // B fragments for both och groups: B[n=ln][k = kg*16 + j] per tap
  const signed char* wba = w8 + (size_t)oa * 576 + kg * 16;
  v4i Ba[9], Bb[9];
#pragma unroll
  for (int t = 0; t < 9; ++t) {
    Ba[t] = *(const v4i*)(wba + t * 64);
    Bb[t] = *(const v4i*)(wba + 9216 + t * 64);   // (oa+16)*576
  }

  const float sw = sw_p[0];
  const float rden = 1.0f / (sw * sa);
  const float boa = bias[oa], bob = bias[oa + 16];
  const float* ctab = (const float*)(lds + 22272);
  const float cFa = ctab[oa];           // interior (case 0) corrections
  const float cFb = ctab[oa + 16];
  float* const outa = out + (size_t)(n * 64 + oa) * 3136 + h0 * 56;
  float* const outb = outa + 16 * 3136;

#pragma unroll 1
  for (int t = 0; t < 7; ++t) {
    const int pb = phalf * 112 + t * 16;          // block-relative px tile base
    const int pa = pb + ln;                       // this lane's A-row px (0..223)
    const int hr = (pa * 9363) >> 19;             // pa / 56 (exact)
    const int wc = pa - hr * 56;
    const signed char* ab = lds + (hr * 58 + wc) * 64 + kg * 16;
    v4i acca = {0, 0, 0, 0}, accb = {0, 0, 0, 0};
#pragma unroll
    for (int kh = 0; kh < 3; ++kh) {
#pragma unroll
      for (int kw = 0; kw < 3; ++kw) {
        const v4i A = *(const v4i*)(ab + (kh * 58 + kw) * 64);
        acca = __builtin_amdgcn_mfma_i32_16x16x64_i8(A, Ba[kh * 3 + kw], acca, 0, 0, 0);
        accb = __builtin_amdgcn_mfma_i32_16x16x64_i8(A, Bb[kh * 3 + kw], accb, 0, 0, 0);
      }
    }
    // epilogue: C/D row(px) = kg*4 + reg, col(och) = ln
    const int pxb = pb + kg * 4;
    float ta[4], tb[4];
#pragma unroll
    for (int e = 0; e < 4; ++e) {
      const int px = pxb + e;
      const int hh = (px * 9363) >> 19;
      const int ww = px - hh * 56;
      const int hg = h0 + hh;
      float ca = cFa, cb = cFb;
      if ((hg == 0) | (hg == 55) | (ww == 0) | (ww == 55)) {   // rare border
        const int vcase = (hg == 0) ? 1 : ((hg == 55) ? 2 : 0);
        const int hcase = (ww == 0) ? 1 : ((ww == 55) ? 2 : 0);
        const int cidx = (vcase * 3 + hcase) * 64;
        ca = ctab[cidx + oa];
        cb = ctab[cidx + oa + 16];
      }
      ta[e] = ((float)acca[e] + ca) * rden + boa;
      tb[e] = ((float)accb[e] + cb) * rden + bob;
    }
    *(float4*)(outa + pxb) = make_float4(ta[0], ta[1], ta[2], ta[3]);
    *(float4*)(outb + pxb) = make_float4(tb[0], tb[1], tb[2], tb[3]);
  }
}

extern "C" void kernel_launch(void* const* d_in, const int* in_sizes, int n_in,
                              void* d_out, int out_size, void* d_ws, size_t ws_size,
                              hipStream_t stream) {
  const float* x    = (const float*)d_in[0];
  const float* wt   = (const float*)d_in[1];
  const float* bias = (const float*)d_in[2];
  const float* sa   = (const float*)d_in[3];
  const float* sw   = (const float*)d_in[4];
  const float* zp   = (const float*)d_in[5];
  float* out = (float*)d_out;

  char* ws = (char*)d_ws;
  signed char* w8 = (signed char*)ws;                 // 36,864 B
  float* corr_tab = (float*)(ws + 36864);             // 2,304 B

  prep_wq<<<64, 64, 0, stream>>>(wt, sw, zp, w8, corr_tab);
  conv_fused<<<dim3(14, 64), 256, 0, stream>>>(x, w8, corr_tab, bias, sa, sw, zp, out);
}

// Round 2
// 125.705 us; speedup vs baseline: 1.0217x; 1.0217x over previous
//
#include <hip/hip_runtime.h>

// ---------------------------------------------------------------------------
// ConvQuantizationWrapper: exact integer reformulation, MFMA i8, fully fused.
// out = [conv3x3(q_in, tc(q_w)) + zp*conv3x3(ones, q_w)] / (sa*sw) + bias
//   q_in = clip(round(x*sa - zp), 0, 255) (u8);  q_w = round(w*sw)
//
// R6: phase 1 restructured. R5's two-stage byte transpose (stride-68 scatter
// + repack, 6 barriers, 16 ds_write_b8 per float4-quad) cost ~20us of serial
// VALU/LDS/barrier work. Now each thread loads 4 float4 from 4 CONSECUTIVE
// channels (lane order cg-fastest: 16 fully-used 64B lines per wave instr),
// quantizes 16 values, packs 4 channel-contiguous dwords and writes them
// DIRECTLY into the final qa layout: 4 ds_write_b32, no repack, ONE
// __syncthreads total. qa row stride padded 64->80B: dword-stride 20 makes
// bank-group (5*rl+kg) mod 8 cycle all 8 quads (5 coprime 8), so both the
// dword writes and phase-2 ds_read_b128 are 2-way max (free, vs previous
// 8-way). Corr table read from L2 in epilogue (no LDS staging).
// ---------------------------------------------------------------------------

typedef int v4i __attribute__((ext_vector_type(4)));

#define ROWB 80   // LDS bytes per qa (row,col) entry: 64 data + 16 pad

// ---- fused weight prep: quantize + 9-case border-correction table ----
__global__ __launch_bounds__(64) void prep_wq(const float* __restrict__ wt,
                                              const float* __restrict__ sw_p,
                                              const float* __restrict__ zp_p,
                                              signed char* __restrict__ w8,
                                              float* __restrict__ corr_tab) {
  const int o = blockIdx.x;             // 0..63
  const int i = threadIdx.x;            // input channel 0..63
  const float sw = sw_p[0];
  const float* wp = wt + (size_t)(o * 64 + i) * 9;
  int q[9];
#pragma unroll
  for (int k = 0; k < 9; ++k) q[k] = (int)rintf(wp[k] * sw);
#pragma unroll
  for (int k = 0; k < 9; ++k)
    w8[(o * 9 + k) * 64 + i] = (signed char)(q[k] & 255);

  int stc[9], srw[9];
#pragma unroll
  for (int k = 0; k < 9; ++k) {
    int a = (int)(signed char)(q[k] & 255);   // two's-complement i8 value
    int b = q[k];
#pragma unroll
    for (int off = 32; off; off >>= 1) {      // xor butterfly: sum in ALL lanes
      a += __shfl_xor(a, off);
      b += __shfl_xor(b, off);
    }
    stc[k] = a; srw[k] = b;
  }
  const float zp = zp_p[0];
  if (i < 9) {                          // lane i computes border case i
    const int v = i / 3, hc = i % 3;
    float corr = 0.0f;
#pragma unroll
    for (int k = 0; k < 9; ++k) {
      const int kh = k / 3, kw = k % 3;
      const bool drop = (v == 1 && kh == 0) || (v == 2 && kh == 2) ||
                        (hc == 1 && kw == 0) || (hc == 2 && kw == 2);
      if (!drop) corr += 128.0f * (float)stc[k] + zp * (float)srw[k];
    }
    corr_tab[i * 64 + o] = corr;
  }
}

// ---- fused quantize + conv: LDS-staged implicit GEMM on mfma_i32_16x16x64 ----
// grid (14, 64): block = one n, 4 output rows (224 px), all 64 och.
// Phase 1: 1536 tasks (= 6*256). idx -> cg = idx&15 (channel group of 4),
// rem = idx>>4, row = rem/14 (qa row 0..5), w4 = rem%14 (pixel quad).
// Phase 2: 4 waves = (px-half) x (och-pair); 7 M-tiles of 16 px each; per
// tile 9 ds_read_b128 A-frags, each feeding 2 MFMAs (och oa, oa+16).
__global__ __launch_bounds__(256, 4) void conv_fused(
    const float* __restrict__ x, const signed char* __restrict__ w8,
    const float* __restrict__ corr_tab, const float* __restrict__ bias,
    const float* __restrict__ sa_p, const float* __restrict__ sw_p,
    const float* __restrict__ zp_p, float* __restrict__ out) {
  __shared__ __align__(16) signed char lds[6 * 58 * ROWB];   // 27,840 B
  const int tid = threadIdx.x;
  const int n = blockIdx.y;
  const int h0 = blockIdx.x * 4;        // output rows h0..h0+3; qa rows h0-1..h0+4
  const float sa = sa_p[0], zp = zp_p[0];
  const float* xim = x + (size_t)n * 200704;    // 64 * 3136

  // ---- phase 1: quantize 6 padded rows directly into LDS ----
#pragma unroll 2
  for (int it = 0; it < 6; ++it) {
    const int idx = tid + 256 * it;     // 0..1535
    if (idx < 1344) {                   // quant tasks
      const int cg = idx & 15;
      const int rem = idx >> 4;         // 0..83
      const int row = (rem * 2341) >> 15;   // rem / 14 (exact, rem < 896)
      const int w4 = rem - row * 14;
      const int ih = h0 - 1 + row;
      const bool valid = (unsigned)ih < 56u;
      int* const dst = (int*)lds + (row * 58 + w4 * 4 + 1) * (ROWB / 4) + cg;
      if (valid) {
        float4 v[4];
#pragma unroll
        for (int j = 0; j < 4; ++j)
          v[j] = *(const float4*)(xim + (size_t)(cg * 4 + j) * 3136 + ih * 56 + w4 * 4);
#pragma unroll
        for (int e = 0; e < 4; ++e) {
          int dw = 0;
#pragma unroll
          for (int j = 0; j < 4; ++j) {
            const float xv = (&v[j].x)[e];
            float tq;
            {
#pragma clang fp contract(off)
              tq = xv * sa - zp;        // match ref: mul then sub, no fma
            }
            float qf = rintf(tq);       // half-to-even, like jnp.round
            qf = fminf(fmaxf(qf, 0.0f), 255.0f);
            const int b = ((int)qf - 128) & 255;
            dw |= b << (8 * j);
          }
          dst[e * (ROWB / 4)] = dw;
        }
      } else {
#pragma unroll
        for (int e = 0; e < 4; ++e) dst[e * (ROWB / 4)] = 0;
      }
    } else {                            // col pads: col 0 and col 57, 6 rows
      const int z = idx - 1344;         // 0..191
      const int loc = z >> 4, d = z & 15;
      const int row = loc >> 1, side = loc & 1;
      ((int*)lds)[(row * 58 + side * 57) * (ROWB / 4) + d] = 0;
    }
  }
  __syncthreads();

  // ---- phase 2: MFMA implicit GEMM ----
  const int lane = tid & 63;
  const int wv = tid >> 6;
  const int phalf = wv & 1;             // px offset 112*phalf
  const int ogp = wv >> 1;              // och 32*ogp
  const int ln = lane & 15;
  const int kg = lane >> 4;             // k-group: bytes kg*16..kg*16+15
  const int oa = ogp * 32 + ln;         // first och; second is oa+16

  // B fragments for both och groups: B[n=ln][k = kg*16 + j] per tap
  const signed char* wba = w8 + (size_t)oa * 576 + kg * 16;
  v4i Ba[9], Bb[9];
#pragma unroll
  for (int t = 0; t < 9; ++t) {
    Ba[t] = *(const v4i*)(wba + t * 64);
    Bb[t] = *(const v4i*)(wba + 9216 + t * 64);   // (oa+16)*576
  }

  const float sw = sw_p[0];
  const float rden = 1.0f / (sw * sa);
  const float boa = bias[oa], bob = bias[oa + 16];
  const float cFa = corr_tab[oa];       // interior (case 0) corrections (L2)
  const float cFb = corr_tab[oa + 16];
  float* const outa = out + (size_t)(n * 64 + oa) * 3136 + h0 * 56;
  float* const outb = outa + 16 * 3136;

#pragma unroll 1
  for (int t = 0; t < 7; ++t) {
    const int pb = phalf * 112 + t * 16;          // block-relative px tile base
    const int pa = pb + ln;                       // this lane's A-row px (0..223)
    const int hr = (pa * 9363) >> 19;             // pa / 56 (exact)
    const int wc = pa - hr * 56;
    const signed char* ab = lds + (hr * 58 + wc) * ROWB + kg * 16;
    v4i acca = {0, 0, 0, 0}, accb = {0, 0, 0, 0};
#pragma unroll
    for (int kh = 0; kh < 3; ++kh) {
#pragma unroll
      for (int kw = 0; kw < 3; ++kw) {
        const v4i A = *(const v4i*)(ab + (kh * 58 + kw) * ROWB);
        acca = __builtin_amdgcn_mfma_i32_16x16x64_i8(A, Ba[kh * 3 + kw], acca, 0, 0, 0);
        accb = __builtin_amdgcn_mfma_i32_16x16x64_i8(A, Bb[kh * 3 + kw], accb, 0, 0, 0);
      }
    }
    // epilogue: C/D row(px) = kg*4 + reg, col(och) = ln
    const int pxb = pb + kg * 4;
    float ta[4], tb[4];
#pragma unroll
    for (int e = 0; e < 4; ++e) {
      const int px = pxb + e;
      const int hh = (px * 9363) >> 19;
      const int ww = px - hh * 56;
      const int hg = h0 + hh;
      float ca = cFa, cb = cFb;
      if ((hg == 0) | (hg == 55) | (ww == 0) | (ww == 55)) {   // rare border
        const int vcase = (hg == 0) ? 1 : ((hg == 55) ? 2 : 0);
        const int hcase = (ww == 0) ? 1 : ((ww == 55) ? 2 : 0);
        const int cidx = (vcase * 3 + hcase) * 64;
        ca = corr_tab[cidx + oa];
        cb = corr_tab[cidx + oa + 16];
      }
      ta[e] = ((float)acca[e] + ca) * rden + boa;
      tb[e] = ((float)accb[e] + cb) * rden + bob;
    }
    *(float4*)(outa + pxb) = make_float4(ta[0], ta[1], ta[2], ta[3]);
    *(float4*)(outb + pxb) = make_float4(tb[0], tb[1], tb[2], tb[3]);
  }
}

extern "C" void kernel_launch(void* const* d_in, const int* in_sizes, int n_in,
                              void* d_out, int out_size, void* d_ws, size_t ws_size,
                              hipStream_t stream) {
  const float* x    = (const float*)d_in[0];
  const float* wt   = (const float*)d_in[1];
  const float* bias = (const float*)d_in[2];
  const float* sa   = (const float*)d_in[3];
  const float* sw   = (const float*)d_in[4];
  const float* zp   = (const float*)d_in[5];
  float* out = (float*)d_out;

  char* ws = (char*)d_ws;
  signed char* w8 = (signed char*)ws;                 // 36,864 B
  float* corr_tab = (float*)(ws + 36864);             // 2,304 B

  prep_wq<<<64, 64, 0, stream>>>(wt, sw, zp, w8, corr_tab);
  conv_fused<<<dim3(14, 64), 256, 0, stream>>>(x, w8, corr_tab, bias, sa, sw, zp, out);
}